// Round 11
// baseline (128.850 us; speedup 1.0000x reference)
//
#include <hip/hip_runtime.h>
#include <math.h>

// Problem constants
#define NN 128
#define LL 1024
#define HH 4
#define DD 64
#define CROWS 128
#define MAGIC 0x5CA1AB1Eu

// ws layout (float index)
//   Wtb   : [128][32 hj][64 k] bf16   @ 0        (131072 floats)
//   cv    : [128][32] f32             @ 131072   (4096)
//   Tp    : [128][8][256] f32         @ 135168   (262144)
//   wtflag: [128][4] u32              @ 397312   (512)
//   tflag : [128][8] u32              @ 397824   (1024)
#define WS_WTB    0
#define WS_CV     131072
#define WS_TP     135168
#define WS_WTFLAG 397312
#define WS_TFLAG  397824

typedef __attribute__((ext_vector_type(8))) short short8;
typedef __attribute__((ext_vector_type(4))) float f32x4;

__device__ __forceinline__ float sigm(float x) {
    return __builtin_amdgcn_rcpf(1.f + __expf(-x));
}

__device__ __forceinline__ unsigned short f2bf(float x) {
    union { float f; unsigned u; } v; v.f = x;
    unsigned r = v.u + 0x7FFFu + ((v.u >> 16) & 1u);   // RNE
    return (unsigned short)(r >> 16);
}

__device__ __forceinline__ short8 pack_bf8(float4 a, float4 b) {
    short8 r;
    r[0] = (short)f2bf(a.x); r[1] = (short)f2bf(a.y);
    r[2] = (short)f2bf(a.z); r[3] = (short)f2bf(a.w);
    r[4] = (short)f2bf(b.x); r[5] = (short)f2bf(b.y);
    r[6] = (short)f2bf(b.z); r[7] = (short)f2bf(b.w);
    return r;
}

// ---------------------------------------------------------------------------
// Single fused kernel. Block b = (n = b>>3, chunk c = b&7).
//   c<4 : produce Wt/cv for (n, h=c) -> ws, release flag (agent scope)
//   all : stage seq chunk bf16 -> LDS; acquire-wait n's 4 flags;
//         MFMA scores -> MLP -> att -> T partial
//   c>0 : T partial -> ws, release flag, exit
//   c==0: wait 7 T flags, reduce T, U = T*Wv^T, out = bu + U*Wu^T
// Idempotent: plain stores only; replay-stale flags are benign (identical
// values rewritten every replay).
// ---------------------------------------------------------------------------
__global__ void __launch_bounds__(256, 4) fused_kernel(
    const float* __restrict__ seq, const float* __restrict__ target,
    const float* __restrict__ memv, const float* __restrict__ Wk,
    const float* __restrict__ Wq, const float* __restrict__ Wv,
    const float* __restrict__ Wu, const float* __restrict__ bu,
    const float* __restrict__ W1, const float* __restrict__ b1,
    const float* __restrict__ W2, const float* __restrict__ b2,
    unsigned short* __restrict__ Wtb, float* __restrict__ cvg,
    float* __restrict__ Tpg, unsigned* __restrict__ wtflag,
    unsigned* __restrict__ tflag,
    float* __restrict__ att_out, float* __restrict__ out)
{
    const int b = blockIdx.x;
    const int n = b >> 3;
    const int c = b & 7;
    const int l0 = c * CROWS;
    const int t = threadIdx.x;
    const int lane = t & 63;
    const int w = t >> 6;

    // phase-1 LDS (production)
    __shared__ __align__(16) float tl[64];
    __shared__ __align__(16) float ml[64];
    __shared__ float vh[64];
    __shared__ float wh[64 * 8];              // [d][j]
    __shared__ float cp[64];
    // phase-2 LDS
    __shared__ __align__(16) short seq_bf[128 * 72];  // [l][k] bf16
    __shared__ __align__(16) short wt_lds[32 * 72];   // [hj][k] bf16
    __shared__ float cvl[32];
    __shared__ __align__(16) float att_l[512];        // [l][h]
    __shared__ __align__(16) float Tp_l[4][256];
    __shared__ float T_l[256];                        // [p = h*64+k]
    __shared__ __align__(16) float U_l[256];
    __shared__ float op[256];
    // total ~34.6 KB -> 4 blocks/CU guaranteed

    // ======================= production (c < 4) ==========================
    if (c < 4) {
        const int h = c;
        if (t < 64)       tl[t] = target[n * 64 + t];
        else if (t < 128) ml[t - 64] = memv[n * 64 + (t - 64)];
        __syncthreads();

        // v[d] = sum_k Wq[h*64+d, k] * target[k]
        {
            const int d = t >> 2, kq = t & 3;
            const float4* wq4 = reinterpret_cast<const float4*>(Wq + (h * 64 + d) * 64 + kq * 16);
            const float4* tl4 = reinterpret_cast<const float4*>(tl + kq * 16);
            float s = 0.f;
            #pragma unroll
            for (int cc = 0; cc < 4; ++cc) {
                const float4 a = wq4[cc], bb = tl4[cc];
                s = fmaf(a.x, bb.x, s); s = fmaf(a.y, bb.y, s);
                s = fmaf(a.z, bb.z, s); s = fmaf(a.w, bb.w, s);
            }
            s += __shfl_xor(s, 1);
            s += __shfl_xor(s, 2);
            if (kq == 0) vh[d] = s;
        }
        __syncthreads();

        // w[d][j] = -W1[j,d] - W1[j,128+d] + W1[j,64+d]*v[d] + W1[j,192+d]*m[d]
        {
            const int d = t & 63, jh = t >> 6;
            const float vv = vh[d], mm = ml[d];
            #pragma unroll
            for (int r = 0; r < 2; ++r) {
                const int j = jh + r * 4;
                float wv = -W1[j * 256 + d] - W1[j * 256 + 128 + d];
                wv = fmaf(W1[j * 256 + 64 + d], vv, wv);
                wv = fmaf(W1[j * 256 + 192 + d], mm, wv);
                wh[d * 8 + j] = wv;
            }
        }
        // c[j] partials
        if (t < 64) {
            const int j = t >> 3, sl = t & 7;
            float s = 0.f;
            #pragma unroll
            for (int d8 = 0; d8 < 8; ++d8) {
                const int d = sl * 8 + d8;
                s = fmaf(W1[j * 256 + d], vh[d], s);
                s = fmaf(W1[j * 256 + 128 + d], ml[d], s);
            }
            cp[t] = s;
        }
        __syncthreads();
        if (t < 8) {
            float s = b1[t];
            #pragma unroll
            for (int sl = 0; sl < 8; ++sl) s += cp[t * 8 + sl];
            cvg[n * 32 + h * 8 + t] = s;
        }

        // Wt[hj][k] = sum_d Wk[h*64+d, k] * w[d][j]; k on lanes
        {
            const int k = t & 63, jp = t >> 6;
            float s0 = 0.f, s1 = 0.f;
            #pragma unroll 8
            for (int d = 0; d < 64; ++d) {
                const float wk = Wk[(h * 64 + d) * 64 + k];
                s0 = fmaf(wk, wh[d * 8 + jp], s0);
                s1 = fmaf(wk, wh[d * 8 + jp + 4], s1);
            }
            unsigned short* dst = Wtb + ((size_t)n * 32 + h * 8) * 64;
            dst[jp * 64 + k]       = f2bf(s0);
            dst[(jp + 4) * 64 + k] = f2bf(s1);
        }
        __syncthreads();   // drains all Wtb/cvg stores (vmcnt 0 before barrier)
        if (t == 0)
            __hip_atomic_store(wtflag + n * 4 + h, MAGIC,
                               __ATOMIC_RELEASE, __HIP_MEMORY_SCOPE_AGENT);
    }

    // ================== stage seq chunk as bf16 (all blocks) ==============
    const float* sbase = seq + ((size_t)n * LL + l0) * 64;
    #pragma unroll
    for (int g = 0; g < 4; ++g) {
        const int p4 = g * 256 + t;
        const int l = p4 >> 3, seg = p4 & 7;
        const float* rp = sbase + l * 64 + seg * 8;
        const float4 a = *reinterpret_cast<const float4*>(rp);
        const float4 bb = *reinterpret_cast<const float4*>(rp + 4);
        *reinterpret_cast<short8*>(seq_bf + l * 72 + seg * 8) = pack_bf8(a, bb);
    }

    // ================== wait for this n's Wt/cv (agent acquire) ===========
    if (t == 0) {
        #pragma unroll
        for (int i = 0; i < 4; ++i) {
            const unsigned* f = wtflag + n * 4 + i;
            while (__hip_atomic_load(f, __ATOMIC_ACQUIRE,
                                     __HIP_MEMORY_SCOPE_AGENT) != MAGIC)
                __builtin_amdgcn_s_sleep(2);
        }
    }
    __syncthreads();

    // ---- stage Wt (bf16, 4KB) + cv into LDS ----
    {
        const int row = t >> 3, seg = t & 7;
        const int4 wv = *reinterpret_cast<const int4*>(
            Wtb + ((size_t)n * 32 + row) * 64 + seg * 8);
        *reinterpret_cast<int4*>(wt_lds + row * 72 + seg * 8) = wv;
    }
    if (t < 32) cvl[t] = cvg[n * 32 + t];
    __syncthreads();

    // ================== score MFMAs ========================================
    const int rt = w & 1;
    const int ctbase = (w >> 1) * 4;
    const int g = lane >> 4;
    const int cidx = lane & 15;

    short8 afrag[2];
    #pragma unroll
    for (int ks = 0; ks < 2; ++ks)
        afrag[ks] = *reinterpret_cast<const short8*>(
            wt_lds + (rt * 16 + cidx) * 72 + ks * 32 + g * 8);

    f32x4 acc[4];
    #pragma unroll
    for (int ct = 0; ct < 4; ++ct)
        #pragma unroll
        for (int r = 0; r < 4; ++r)
            acc[ct][r] = cvl[rt * 16 + g * 4 + r];

    #pragma unroll
    for (int ct = 0; ct < 4; ++ct) {
        const int l = (ctbase + ct) * 16 + cidx;
        const short8 bf0 = *reinterpret_cast<const short8*>(seq_bf + l * 72 + g * 8);
        const short8 bf1 = *reinterpret_cast<const short8*>(seq_bf + l * 72 + 32 + g * 8);
        acc[ct] = __builtin_amdgcn_mfma_f32_16x16x32_bf16(afrag[0], bf0, acc[ct], 0, 0, 0);
        acc[ct] = __builtin_amdgcn_mfma_f32_16x16x32_bf16(afrag[1], bf1, acc[ct], 0, 0, 0);
    }

    // ================== MLP + att ==========================================
    {
        const float4 w2v = *reinterpret_cast<const float4*>(W2 + 4 * (g & 1));
        const float b2v = b2[0];
        #pragma unroll
        for (int ct = 0; ct < 4; ++ct) {
            float local = w2v.x * sigm(acc[ct][0]);
            local = fmaf(w2v.y, sigm(acc[ct][1]), local);
            local = fmaf(w2v.z, sigm(acc[ct][2]), local);
            local = fmaf(w2v.w, sigm(acc[ct][3]), local);
            local += __shfl_xor(local, 16);
            const float attv = sigm(b2v + local);
            if ((lane & 16) == 0) {
                const int l = (ctbase + ct) * 16 + cidx;
                const int h = 2 * rt + (g >> 1);
                att_l[l * 4 + h] = attv;
            }
        }
    }
    __syncthreads();

    // ---- att store: 512 contiguous floats ----
    {
        float* dst = att_out + ((size_t)n * LL + l0) * 4;
        dst[t] = att_l[t];
        dst[256 + t] = att_l[256 + t];
    }

    // ================== T partials =========================================
    {
        float th0 = 0.f, th1 = 0.f, th2 = 0.f, th3 = 0.f;
        const float* sq = sbase + (w * 32) * 64 + lane;
        #pragma unroll 4
        for (int li = 0; li < 32; ++li) {
            const float s = sq[li * 64];
            const float4 a = *reinterpret_cast<const float4*>(att_l + (w * 32 + li) * 4);
            th0 = fmaf(a.x, s, th0); th1 = fmaf(a.y, s, th1);
            th2 = fmaf(a.z, s, th2); th3 = fmaf(a.w, s, th3);
        }
        Tp_l[w][0 * 64 + lane] = th0;
        Tp_l[w][1 * 64 + lane] = th1;
        Tp_l[w][2 * 64 + lane] = th2;
        Tp_l[w][3 * 64 + lane] = th3;
    }
    __syncthreads();

    T_l[t] = Tp_l[0][t] + Tp_l[1][t] + Tp_l[2][t] + Tp_l[3][t];
    __syncthreads();

    // ================== chunk reduction / epilogue =========================
    if (c > 0) {
        Tpg[((size_t)n * 8 + c) * 256 + t] = T_l[t];
        __syncthreads();   // drain stores
        if (t == 0)
            __hip_atomic_store(tflag + n * 8 + c, MAGIC,
                               __ATOMIC_RELEASE, __HIP_MEMORY_SCOPE_AGENT);
        return;
    }

    // c == 0: gather 7 sibling partials
    if (t == 0) {
        #pragma unroll
        for (int i = 1; i < 8; ++i) {
            const unsigned* f = tflag + n * 8 + i;
            while (__hip_atomic_load(f, __ATOMIC_ACQUIRE,
                                     __HIP_MEMORY_SCOPE_AGENT) != MAGIC)
                __builtin_amdgcn_s_sleep(2);
        }
    }
    __syncthreads();

    {
        float s = T_l[t];
        #pragma unroll
        for (int i = 1; i < 8; ++i)
            s += Tpg[((size_t)n * 8 + i) * 256 + t];
        T_l[t] = s;
    }
    __syncthreads();

    // U[hd] = sum_k T[h][k] * Wv[hd][k]
    {
        const int h = t >> 6;
        const float4* wv4 = reinterpret_cast<const float4*>(Wv + t * 64);
        const float4* t4  = reinterpret_cast<const float4*>(T_l + h * 64);
        float s = 0.f;
        #pragma unroll
        for (int kq = 0; kq < 16; ++kq) {
            const float4 a = wv4[kq], bb = t4[kq];
            s = fmaf(a.x, bb.x, s); s = fmaf(a.y, bb.y, s);
            s = fmaf(a.z, bb.z, s); s = fmaf(a.w, bb.w, s);
        }
        U_l[t] = s;
    }
    __syncthreads();

    // out[q] = bu[q] + sum_hd U[hd] * Wu[q][hd]
    {
        const int q = t & 63, qr = t >> 6;
        const float4* wu4 = reinterpret_cast<const float4*>(Wu + q * 256 + qr * 64);
        const float4* u4  = reinterpret_cast<const float4*>(U_l + qr * 64);
        float s = 0.f;
        #pragma unroll
        for (int i = 0; i < 16; ++i) {
            const float4 a = wu4[i], bb = u4[i];
            s = fmaf(a.x, bb.x, s); s = fmaf(a.y, bb.y, s);
            s = fmaf(a.z, bb.z, s); s = fmaf(a.w, bb.w, s);
        }
        op[t] = s;
    }
    __syncthreads();
    if (t < 64)
        out[n * 64 + t] = bu[t] + op[t] + op[64 + t] + op[128 + t] + op[192 + t];
}

extern "C" void kernel_launch(void* const* d_in, const int* in_sizes, int n_in,
                              void* d_out, int out_size, void* d_ws, size_t ws_size,
                              hipStream_t stream) {
    const float* seq    = (const float*)d_in[0];
    const float* target = (const float*)d_in[1];
    const float* memv   = (const float*)d_in[2];
    const float* Wk     = (const float*)d_in[3];
    const float* Wq     = (const float*)d_in[4];
    const float* Wv     = (const float*)d_in[5];
    const float* Wu     = (const float*)d_in[6];
    const float* bu     = (const float*)d_in[7];
    const float* W1     = (const float*)d_in[8];
    const float* b1     = (const float*)d_in[9];
    const float* W2     = (const float*)d_in[10];
    const float* b2     = (const float*)d_in[11];

    float* out = (float*)d_out;             // [128*64]
    float* att = out + NN * DD;             // [128*1024*4]

    float* ws = (float*)d_ws;
    unsigned short* Wtb = (unsigned short*)(ws + WS_WTB);
    float* cvg          = ws + WS_CV;
    float* Tpg          = ws + WS_TP;
    unsigned* wtflag    = (unsigned*)(ws + WS_WTFLAG);
    unsigned* tflag     = (unsigned*)(ws + WS_TFLAG);

    fused_kernel<<<NN * 8, 256, 0, stream>>>(seq, target, memv, Wk, Wq, Wv, Wu,
                                             bu, W1, b1, W2, b2,
                                             Wtb, cvg, Tpg, wtflag, tflag,
                                             att, out);
}

// Round 12
// 25.082 us; speedup vs baseline: 5.1372x; 5.1372x over previous
//
#include <hip/hip_runtime.h>
#include <math.h>

// Problem constants
#define NN 128
#define LL 1024
#define HH 4
#define DD 64

typedef __attribute__((ext_vector_type(8))) short short8;
typedef __attribute__((ext_vector_type(4))) float f32x4;

__device__ __forceinline__ float sigm(float x) {
    return __builtin_amdgcn_rcpf(1.f + __expf(-x));
}

__device__ __forceinline__ unsigned short f2bf(float x) {
    union { float f; unsigned u; } v; v.f = x;
    unsigned r = v.u + 0x7FFFu + ((v.u >> 16) & 1u);   // RNE
    return (unsigned short)(r >> 16);
}

__device__ __forceinline__ short8 pack_bf8(float4 a, float4 b) {
    short8 r;
    r[0] = (short)f2bf(a.x); r[1] = (short)f2bf(a.y);
    r[2] = (short)f2bf(a.z); r[3] = (short)f2bf(a.w);
    r[4] = (short)f2bf(b.x); r[5] = (short)f2bf(b.y);
    r[6] = (short)f2bf(b.z); r[7] = (short)f2bf(b.w);
    return r;
}

// ---------------------------------------------------------------------------
// ONE block per n (grid 128, 1024 threads). No cross-block deps, no ws.
//   phase A: production — group gg = t>>8 computes head h=gg's v, w, c, Wt
//            directly into LDS (wt_lds bf16 [hj][k], cvl[32])
//   phase B: 4 sub-chunks of 256 rows:
//            stage seq bf16 -> MFMA scores -> MLP -> att store -> T accum (regs)
//   phase C: reduce T partials, U = T*Wv^T, out = bu + U*Wu^T
// ---------------------------------------------------------------------------
__global__ void __launch_bounds__(1024, 4) fused_kernel(
    const float* __restrict__ seq, const float* __restrict__ target,
    const float* __restrict__ memv, const float* __restrict__ Wk,
    const float* __restrict__ Wq, const float* __restrict__ Wv,
    const float* __restrict__ Wu, const float* __restrict__ bu,
    const float* __restrict__ W1, const float* __restrict__ b1,
    const float* __restrict__ W2, const float* __restrict__ b2,
    float* __restrict__ att_out, float* __restrict__ out)
{
    const int n = blockIdx.x;
    const int t = threadIdx.x;
    const int lane = t & 63;
    const int w = t >> 6;          // wave 0..15

    // production LDS
    __shared__ __align__(16) float tl[64];
    __shared__ __align__(16) float ml[64];
    __shared__ float vh[4][64];
    __shared__ float wh[4][512];             // [h][d*8+j]
    __shared__ float cp[4][64];
    // main LDS
    __shared__ float cvl[32];
    __shared__ __align__(16) short wt_lds[32 * 72];   // [hj][k] bf16
    __shared__ __align__(16) short seq_bf[256 * 72];  // [l][k] bf16
    __shared__ __align__(16) float att_l[1024];       // [l][h]
    __shared__ __align__(16) float Tp_l[16][256];     // per-wave T partials
    __shared__ float T_l[256];                        // [p = h*64+k]
    __shared__ __align__(16) float U_l[256];
    __shared__ float op[16 * 64];
    // ~73 KB total

    // ======================= phase A: production =========================
    const int gg = t >> 8;        // group = head h
    const int tt = t & 255;
    const int h = gg;

    if (t < 64)       tl[t] = target[n * 64 + t];
    else if (t < 128) ml[t - 64] = memv[n * 64 + (t - 64)];
    __syncthreads();

    // v[h][d] = sum_k Wq[h*64+d, k] * target[k]
    {
        const int d = tt >> 2, kq = tt & 3;
        const float4* wq4 = reinterpret_cast<const float4*>(Wq + (h * 64 + d) * 64 + kq * 16);
        const float4* tl4 = reinterpret_cast<const float4*>(tl + kq * 16);
        float s = 0.f;
        #pragma unroll
        for (int cc = 0; cc < 4; ++cc) {
            const float4 a = wq4[cc], bb = tl4[cc];
            s = fmaf(a.x, bb.x, s); s = fmaf(a.y, bb.y, s);
            s = fmaf(a.z, bb.z, s); s = fmaf(a.w, bb.w, s);
        }
        s += __shfl_xor(s, 1);
        s += __shfl_xor(s, 2);
        if (kq == 0) vh[h][d] = s;
    }
    __syncthreads();

    // w[h][d][j] = -W1[j,d] - W1[j,128+d] + W1[j,64+d]*v[d] + W1[j,192+d]*m[d]
    {
        const int d = tt & 63, jh = tt >> 6;
        const float vv = vh[h][d], mm = ml[d];
        #pragma unroll
        for (int r = 0; r < 2; ++r) {
            const int j = jh + r * 4;
            float wv = -W1[j * 256 + d] - W1[j * 256 + 128 + d];
            wv = fmaf(W1[j * 256 + 64 + d], vv, wv);
            wv = fmaf(W1[j * 256 + 192 + d], mm, wv);
            wh[h][d * 8 + j] = wv;
        }
    }
    // c partials
    if (tt < 64) {
        const int j = tt >> 3, sl = tt & 7;
        float s = 0.f;
        #pragma unroll
        for (int d8 = 0; d8 < 8; ++d8) {
            const int d = sl * 8 + d8;
            s = fmaf(W1[j * 256 + d], vh[h][d], s);
            s = fmaf(W1[j * 256 + 128 + d], ml[d], s);
        }
        cp[h][tt] = s;
    }
    __syncthreads();
    if (tt < 8) {
        float s = b1[tt];
        #pragma unroll
        for (int sl = 0; sl < 8; ++sl) s += cp[h][tt * 8 + sl];
        cvl[h * 8 + tt] = s;
    }

    // Wt[hj][k] = sum_d Wk[h*64+d, k] * w[h][d][j]; k on lanes (coalesced)
    {
        const int k = tt & 63, jp = tt >> 6;
        float s0 = 0.f, s1 = 0.f;
        #pragma unroll 8
        for (int d = 0; d < 64; ++d) {
            const float wk = Wk[(h * 64 + d) * 64 + k];
            s0 = fmaf(wk, wh[h][d * 8 + jp], s0);
            s1 = fmaf(wk, wh[h][d * 8 + jp + 4], s1);
        }
        wt_lds[(h * 8 + jp) * 72 + k]     = (short)f2bf(s0);
        wt_lds[(h * 8 + jp + 4) * 72 + k] = (short)f2bf(s1);
    }
    __syncthreads();

    // ======================= phase B: sub-chunk loop ======================
    const float* sbase = seq + (size_t)n * LL * 64;

    const int rt = w & 1;            // hj 16-block
    const int ctA = w >> 1;          // coltiles ctA and ctA+8
    const int g = lane >> 4;         // k-group / C-row group
    const int cidx = lane & 15;      // col within tile

    short8 afrag[2];
    #pragma unroll
    for (int ks = 0; ks < 2; ++ks)
        afrag[ks] = *reinterpret_cast<const short8*>(
            wt_lds + (rt * 16 + cidx) * 72 + ks * 32 + g * 8);

    const float4 w2v = *reinterpret_cast<const float4*>(W2 + 4 * (g & 1));
    const float b2v = b2[0];
    const float cv0 = cvl[rt * 16 + g * 4 + 0];
    const float cv1 = cvl[rt * 16 + g * 4 + 1];
    const float cv2 = cvl[rt * 16 + g * 4 + 2];
    const float cv3 = cvl[rt * 16 + g * 4 + 3];

    float th0 = 0.f, th1 = 0.f, th2 = 0.f, th3 = 0.f;   // T accum over chunks

    for (int sc = 0; sc < 4; ++sc) {
        const float* scb = sbase + sc * 256 * 64;

        // ---- stage 256 rows as bf16 (each thread: 2 x 32B contiguous) ----
        #pragma unroll
        for (int gsg = 0; gsg < 2; ++gsg) {
            const int p8 = gsg * 1024 + t;
            const int l = p8 >> 3, seg = p8 & 7;
            const float* rp = scb + l * 64 + seg * 8;
            const float4 a = *reinterpret_cast<const float4*>(rp);
            const float4 bb = *reinterpret_cast<const float4*>(rp + 4);
            *reinterpret_cast<short8*>(seq_bf + l * 72 + seg * 8) = pack_bf8(a, bb);
        }
        __syncthreads();

        // ---- score MFMAs + MLP for coltiles ctA, ctA+8 ----
        #pragma unroll
        for (int cc = 0; cc < 2; ++cc) {
            const int ct = ctA + cc * 8;
            const int l = ct * 16 + cidx;
            f32x4 acc;
            acc[0] = cv0; acc[1] = cv1; acc[2] = cv2; acc[3] = cv3;
            const short8 bf0 = *reinterpret_cast<const short8*>(seq_bf + l * 72 + g * 8);
            const short8 bf1 = *reinterpret_cast<const short8*>(seq_bf + l * 72 + 32 + g * 8);
            acc = __builtin_amdgcn_mfma_f32_16x16x32_bf16(afrag[0], bf0, acc, 0, 0, 0);
            acc = __builtin_amdgcn_mfma_f32_16x16x32_bf16(afrag[1], bf1, acc, 0, 0, 0);

            float local = w2v.x * sigm(acc[0]);
            local = fmaf(w2v.y, sigm(acc[1]), local);
            local = fmaf(w2v.z, sigm(acc[2]), local);
            local = fmaf(w2v.w, sigm(acc[3]), local);
            local += __shfl_xor(local, 16);
            const float attv = sigm(b2v + local);
            if ((lane & 16) == 0) {
                const int hh = 2 * rt + (g >> 1);
                att_l[l * 4 + hh] = attv;
            }
        }
        __syncthreads();

        // ---- att store: 1024 contiguous floats ----
        att_out[((size_t)n * LL + sc * 256) * 4 + t] = att_l[t];

        // ---- T accumulation: wave w covers rows [16w, 16w+16); lane = k ----
        {
            const float* sq = scb + (w * 16) * 64 + lane;
            #pragma unroll 4
            for (int li = 0; li < 16; ++li) {
                const float s = sq[li * 64];                  // coalesced, L2-hot
                const float4 a = *reinterpret_cast<const float4*>(att_l + (w * 16 + li) * 4);
                th0 = fmaf(a.x, s, th0); th1 = fmaf(a.y, s, th1);
                th2 = fmaf(a.z, s, th2); th3 = fmaf(a.w, s, th3);
            }
        }
        // next iteration's first __syncthreads() orders att_l reuse
    }

    Tp_l[w][0 * 64 + lane] = th0;
    Tp_l[w][1 * 64 + lane] = th1;
    Tp_l[w][2 * 64 + lane] = th2;
    Tp_l[w][3 * 64 + lane] = th3;
    __syncthreads();

    // ======================= phase C: epilogue ============================
    if (t < 256) {
        float s = 0.f;
        #pragma unroll
        for (int i = 0; i < 16; ++i) s += Tp_l[i][t];
        T_l[t] = s;
    }
    __syncthreads();

    // U[hd] = sum_k T[h][k] * Wv[hd][k]; thread = (hd, k-quarter)
    {
        const int hd = t >> 2, kq = t & 3;
        const int hq = hd >> 6;
        const float4* wv4 = reinterpret_cast<const float4*>(Wv + hd * 64 + kq * 16);
        const float4* t4  = reinterpret_cast<const float4*>(T_l + hq * 64 + kq * 16);
        float s = 0.f;
        #pragma unroll
        for (int i = 0; i < 4; ++i) {
            const float4 a = wv4[i], bb = t4[i];
            s = fmaf(a.x, bb.x, s); s = fmaf(a.y, bb.y, s);
            s = fmaf(a.z, bb.z, s); s = fmaf(a.w, bb.w, s);
        }
        s += __shfl_xor(s, 1);
        s += __shfl_xor(s, 2);
        if (kq == 0) U_l[hd] = s;
    }
    __syncthreads();

    // out[q] = bu[q] + sum_hd U[hd]*Wu[q][hd]; thread = (q, 16-hd slice)
    {
        const int q = t & 63, qr = t >> 6;
        const float4* wu4 = reinterpret_cast<const float4*>(Wu + q * 256 + qr * 16);
        const float4* u4  = reinterpret_cast<const float4*>(U_l + qr * 16);
        float s = 0.f;
        #pragma unroll
        for (int i = 0; i < 4; ++i) {
            const float4 a = wu4[i], bb = u4[i];
            s = fmaf(a.x, bb.x, s); s = fmaf(a.y, bb.y, s);
            s = fmaf(a.z, bb.z, s); s = fmaf(a.w, bb.w, s);
        }
        op[qr * 64 + q] = s;
    }
    __syncthreads();
    if (t < 64) {
        float s = bu[t];
        #pragma unroll
        for (int qr = 0; qr < 16; ++qr) s += op[qr * 64 + t];
        out[n * 64 + t] = s;
    }
}

extern "C" void kernel_launch(void* const* d_in, const int* in_sizes, int n_in,
                              void* d_out, int out_size, void* d_ws, size_t ws_size,
                              hipStream_t stream) {
    const float* seq    = (const float*)d_in[0];
    const float* target = (const float*)d_in[1];
    const float* memv   = (const float*)d_in[2];
    const float* Wk     = (const float*)d_in[3];
    const float* Wq     = (const float*)d_in[4];
    const float* Wv     = (const float*)d_in[5];
    const float* Wu     = (const float*)d_in[6];
    const float* bu     = (const float*)d_in[7];
    const float* W1     = (const float*)d_in[8];
    const float* b1     = (const float*)d_in[9];
    const float* W2     = (const float*)d_in[10];
    const float* b2     = (const float*)d_in[11];

    float* out = (float*)d_out;             // [128*64]
    float* att = out + NN * DD;             // [128*1024*4]

    fused_kernel<<<NN, 1024, 0, stream>>>(seq, target, memv, Wk, Wq, Wv, Wu,
                                          bu, W1, b1, W2, b2, att, out);
}